// Round 1
// baseline (587.169 us; speedup 1.0000x reference)
//
#include <hip/hip_runtime.h>
#include <cmath>

#define LRALPHA 0.2f

namespace {
constexpr int BB = 4;
constexpr int NN = 4096;
constexpr int ROWS = BB * NN;   // 16384
}

// ---------- tiny prep kernels ----------

__global__ void k_transpose_w(const float* __restrict__ W, float* __restrict__ Wt) {
  int t = blockIdx.x * 256 + threadIdx.x;      // 4096 threads total
  int k = t >> 6, c = t & 63;
  Wt[c * 64 + k] = W[k * 64 + c];
}

// h = features @ W  (wave per row, lane = out channel), plus s1 = h.a1, s2 = h.a2
__global__ void k_h(const float* __restrict__ feat, const float* __restrict__ Wt,
                    const float* __restrict__ a, float* __restrict__ h,
                    float* __restrict__ s1g, float* __restrict__ s2g) {
  int lane = threadIdx.x & 63;
  int wave = threadIdx.x >> 6;
  int row = blockIdx.x * 4 + wave;
  const float4* f4 = (const float4*)(feat + (size_t)row * 64);   // wave-uniform -> s_load
  const float4* w4 = (const float4*)(Wt + (size_t)lane * 64);
  float hv = 0.f;
#pragma unroll
  for (int kk = 0; kk < 16; ++kk) {
    float4 f = f4[kk], w = w4[kk];
    hv = fmaf(f.x, w.x, hv); hv = fmaf(f.y, w.y, hv);
    hv = fmaf(f.z, w.z, hv); hv = fmaf(f.w, w.w, hv);
  }
  h[(size_t)row * 64 + lane] = hv;
  float p1 = hv * a[lane];
  float p2 = hv * a[64 + lane];
#pragma unroll
  for (int off = 32; off; off >>= 1) {
    p1 += __shfl_xor(p1, off, 64);
    p2 += __shfl_xor(p2, off, 64);
  }
  if (lane == 0) { s1g[row] = p1; s2g[row] = p2; }
}

// per-batch max of s2 (monotone lrelu => row max of e is lrelu(s1_i + max s2))
__global__ void k_maxs2(const float* __restrict__ s2g, float* __restrict__ maxs2) {
  __shared__ float red[256];
  int b = blockIdx.x;
  float m = -1e30f;
  for (int j = threadIdx.x; j < NN; j += 256) m = fmaxf(m, s2g[b * NN + j]);
  red[threadIdx.x] = m;
  __syncthreads();
  for (int off = 128; off; off >>= 1) {
    if ((int)threadIdx.x < off) red[threadIdx.x] = fmaxf(red[threadIdx.x], red[threadIdx.x + off]);
    __syncthreads();
  }
  if (threadIdx.x == 0) maxs2[b] = red[0];
}

// A = exp(s1-m), A' = exp(0.2*s1-m); params[j] = (s2, exp(s2), exp(0.2*s2), 0)
__global__ void k_prep(const float* __restrict__ s1g, const float* __restrict__ s2g,
                       const float* __restrict__ maxs2,
                       float* __restrict__ Ag, float* __restrict__ Apg,
                       float4* __restrict__ params) {
  int row = blockIdx.x * 256 + threadIdx.x;
  int b = row >> 12;
  float s1 = s1g[row], s2 = s2g[row];
  float t = s1 + maxs2[b];
  float m = t >= 0.f ? t : LRALPHA * t;
  Ag[row]  = __expf(s1 - m) * 0.f + expf(s1 - m);          // keep precise expf
  Apg[row] = expf(LRALPHA * s1 - m);
  params[row] = make_float4(s2, expf(s2), expf(LRALPHA * s2), 0.f);
}

// ---------- main attention kernel ----------
// w_ij = (s1_i+s2_j>=0) ? A_i*B_j : A'_i*B'_j  -- no exp in the hot loop.
// Thread: 4 rows x 16 channels. Block: 256 rows. grid = (64 rowblocks, slices).
__global__ __launch_bounds__(256) void k_attn(
    const float* __restrict__ h, const float* __restrict__ s1g,
    const float* __restrict__ Ag, const float* __restrict__ Apg,
    const float4* __restrict__ params,
    float* __restrict__ acc_part, float* __restrict__ l_part, int slices) {
  const int rowblock = blockIdx.x;          // 0..63
  const int slice = blockIdx.y;             // 0..slices-1
  const int slot = threadIdx.x >> 2;        // 0..63
  const int cg = threadIdx.x & 3;           // 0..3 (16 channels each)
  const int row0 = rowblock * 256 + slot * 4;
  const int b = rowblock >> 4;              // 16 rowblocks per batch (uniform)
  const int jlen = NN / slices;
  const int j0 = b * NN + slice * jlen;

  float s1r[4], Ar[4], Apr[4], l[4];
  float4 acc[4][4];
#pragma unroll
  for (int r = 0; r < 4; ++r) {
    s1r[r] = s1g[row0 + r];
    Ar[r]  = Ag[row0 + r];
    Apr[r] = Apg[row0 + r];
    l[r] = 0.f;
#pragma unroll
    for (int q = 0; q < 4; ++q) acc[r][q] = make_float4(0.f, 0.f, 0.f, 0.f);
  }

  for (int j = j0; j < j0 + jlen; ++j) {
    float4 p = params[j];                   // uniform -> s_load_dwordx4
    const float4* hp = (const float4*)(h + ((size_t)j << 6) + (cg << 4));
    float4 h0 = hp[0], h1 = hp[1], h2 = hp[2], h3 = hp[3];
#pragma unroll
    for (int r = 0; r < 4; ++r) {
      float t = s1r[r] + p.x;
      bool pos = (t >= 0.f);
      float w = (pos ? Ar[r] : Apr[r]) * (pos ? p.y : p.z);
      l[r] += w;
      acc[r][0].x = fmaf(w, h0.x, acc[r][0].x); acc[r][0].y = fmaf(w, h0.y, acc[r][0].y);
      acc[r][0].z = fmaf(w, h0.z, acc[r][0].z); acc[r][0].w = fmaf(w, h0.w, acc[r][0].w);
      acc[r][1].x = fmaf(w, h1.x, acc[r][1].x); acc[r][1].y = fmaf(w, h1.y, acc[r][1].y);
      acc[r][1].z = fmaf(w, h1.z, acc[r][1].z); acc[r][1].w = fmaf(w, h1.w, acc[r][1].w);
      acc[r][2].x = fmaf(w, h2.x, acc[r][2].x); acc[r][2].y = fmaf(w, h2.y, acc[r][2].y);
      acc[r][2].z = fmaf(w, h2.z, acc[r][2].z); acc[r][2].w = fmaf(w, h2.w, acc[r][2].w);
      acc[r][3].x = fmaf(w, h3.x, acc[r][3].x); acc[r][3].y = fmaf(w, h3.y, acc[r][3].y);
      acc[r][3].z = fmaf(w, h3.z, acc[r][3].z); acc[r][3].w = fmaf(w, h3.w, acc[r][3].w);
    }
  }

#pragma unroll
  for (int r = 0; r < 4; ++r) {
    size_t idx = ((size_t)slice * ROWS + row0 + r) * 64 + (cg << 4);
    float4* o = (float4*)(acc_part + idx);
    o[0] = acc[r][0]; o[1] = acc[r][1]; o[2] = acc[r][2]; o[3] = acc[r][3];
    if (cg == 0) l_part[(size_t)slice * ROWS + row0 + r] = l[r];
  }
}

// out = sum_slices acc / sum_slices l   (works in-place when acc_part == out, slices==1)
__global__ void k_finish(const float* __restrict__ acc_part, const float* __restrict__ l_part,
                         float* __restrict__ out, int slices) {
  int gid = blockIdx.x * 256 + threadIdx.x;    // 0..ROWS*64-1
  int row = gid >> 6;
  float s = 0.f, L = 0.f;
  for (int sl = 0; sl < slices; ++sl) {
    s += acc_part[(size_t)sl * ROWS * 64 + gid];
    L += l_part[(size_t)sl * ROWS + row];
  }
  out[gid] = s / L;
}

// ---------- launcher ----------

extern "C" void kernel_launch(void* const* d_in, const int* in_sizes, int n_in,
                              void* d_out, int out_size, void* d_ws, size_t ws_size,
                              hipStream_t stream) {
  const float* feat = (const float*)d_in[0];
  // d_in[1] = adj : UNUSED by the reference computation
  const float* W = (const float*)d_in[2];
  const float* a = (const float*)d_in[3];
  float* out = (float*)d_out;

  char* ws = (char*)d_ws;
  size_t off = 0;
  auto carve = [&](size_t bytes) -> char* {
    char* p = ws + off;
    off = (off + bytes + 255) & ~(size_t)255;
    return p;
  };
  float*  h      = (float*)carve((size_t)ROWS * 64 * sizeof(float));   // 4 MB
  float*  Wt     = (float*)carve(64 * 64 * sizeof(float));
  float*  s1g    = (float*)carve(ROWS * sizeof(float));
  float*  s2g    = (float*)carve(ROWS * sizeof(float));
  float*  Ag     = (float*)carve(ROWS * sizeof(float));
  float*  Apg    = (float*)carve(ROWS * sizeof(float));
  float4* params = (float4*)carve(ROWS * sizeof(float4));
  float*  maxs2  = (float*)carve(16 * sizeof(float));
  float*  l_part = (float*)carve((size_t)8 * ROWS * sizeof(float));    // up to 8 slices

  size_t accSlice = (size_t)ROWS * 64 * sizeof(float);                 // 4 MB per slice
  size_t remaining = (ws_size > off) ? (ws_size - off) : 0;
  int slices = 8;
  while (slices > 1 && (size_t)slices * accSlice > remaining) slices >>= 1;
  float* acc_part;
  if (accSlice <= remaining) {
    acc_part = (float*)(ws + off);
  } else {
    acc_part = out;   // fallback: accumulate directly into d_out, normalize in-place
    slices = 1;
  }

  k_transpose_w<<<16, 256, 0, stream>>>(W, Wt);
  k_h<<<ROWS / 4, 256, 0, stream>>>(feat, Wt, a, h, s1g, s2g);
  k_maxs2<<<BB, 256, 0, stream>>>(s2g, maxs2);
  k_prep<<<ROWS / 256, 256, 0, stream>>>(s1g, s2g, maxs2, Ag, Apg, params);
  k_attn<<<dim3(64, slices), 256, 0, stream>>>(h, s1g, Ag, Apg, params,
                                               acc_part, l_part, slices);
  k_finish<<<(ROWS * 64) / 256, 256, 0, stream>>>(acc_part, l_part, out, slices);
}

// Round 4
// 414.694 us; speedup vs baseline: 1.4159x; 1.4159x over previous
//
#include <hip/hip_runtime.h>
#include <hip/hip_bf16.h>
#include <cmath>

#define LRALPHA 0.2f

namespace {
constexpr int BB = 4;
constexpr int NN = 4096;
constexpr int ROWS = BB * NN;   // 16384
}

typedef __attribute__((ext_vector_type(8))) short bf16x8;
typedef __attribute__((ext_vector_type(4))) float f32x4;

static __device__ inline short f2bf(float x) {
  __hip_bfloat16 t = __float2bfloat16(x);
  return *reinterpret_cast<short*>(&t);
}
static __device__ inline float bf2f(short x) {
  __hip_bfloat16 t = *reinterpret_cast<__hip_bfloat16*>(&x);
  return __bfloat162float(t);
}

// ---------- tiny prep kernels ----------

__global__ void k_transpose_w(const float* __restrict__ W, float* __restrict__ Wt) {
  int t = blockIdx.x * 256 + threadIdx.x;      // 4096 threads total
  int k = t >> 6, c = t & 63;
  Wt[c * 64 + k] = W[k * 64 + c];
}

// h = features @ W  (wave per row, lane = out channel), plus s1 = h.a1, s2 = h.a2
__global__ void k_h(const float* __restrict__ feat, const float* __restrict__ Wt,
                    const float* __restrict__ a, float* __restrict__ h,
                    float* __restrict__ s1g, float* __restrict__ s2g) {
  int lane = threadIdx.x & 63;
  int wave = threadIdx.x >> 6;
  int row = blockIdx.x * 4 + wave;
  const float4* f4 = (const float4*)(feat + (size_t)row * 64);   // wave-uniform
  const float4* w4 = (const float4*)(Wt + (size_t)lane * 64);
  float hv = 0.f;
#pragma unroll
  for (int kk = 0; kk < 16; ++kk) {
    float4 f = f4[kk], w = w4[kk];
    hv = fmaf(f.x, w.x, hv); hv = fmaf(f.y, w.y, hv);
    hv = fmaf(f.z, w.z, hv); hv = fmaf(f.w, w.w, hv);
  }
  h[(size_t)row * 64 + lane] = hv;
  float p1 = hv * a[lane];
  float p2 = hv * a[64 + lane];
#pragma unroll
  for (int off = 32; off; off >>= 1) {
    p1 += __shfl_xor(p1, off, 64);
    p2 += __shfl_xor(p2, off, 64);
  }
  if (lane == 0) { s1g[row] = p1; s2g[row] = p2; }
}

// h (fp32 [b*N+n][c]) -> hi/lo bf16 pair, transposed: hT*[b*64+c][n]
// h = hi + lo to ~2^-18 relative (double-bf16 split for fp32-grade MFMA).
__global__ __launch_bounds__(256) void k_cvt(const float* __restrict__ h,
                                             unsigned short* __restrict__ hTh,
                                             unsigned short* __restrict__ hTl) {
  __shared__ float tile[64][65];
  int n0 = blockIdx.x * 64;     // n-tile within batch
  int b  = blockIdx.y;          // 0..3
  int c  = threadIdx.x & 63;
  int r4 = threadIdx.x >> 6;    // 0..3
#pragma unroll
  for (int rr = 0; rr < 16; ++rr) {
    int n = rr * 4 + r4;
    tile[n][c] = h[((size_t)(b * NN + n0 + n)) * 64 + c];   // coalesced
  }
  __syncthreads();
  int n  = threadIdx.x & 63;
  int c4 = threadIdx.x >> 6;
#pragma unroll
  for (int cc = 0; cc < 16; ++cc) {
    int ch = cc * 4 + c4;
    float v = tile[n][ch];
    short hi = f2bf(v);
    short lo = f2bf(v - bf2f(hi));
    size_t idx = ((size_t)(b * 64 + ch) << 12) + n0 + n;
    hTh[idx] = (unsigned short)hi;
    hTl[idx] = (unsigned short)lo;
  }
}

// per-batch max of s2 (monotone lrelu => row max of e is lrelu(s1_i + max s2))
__global__ void k_maxs2(const float* __restrict__ s2g, float* __restrict__ maxs2) {
  __shared__ float red[256];
  int b = blockIdx.x;
  float m = -1e30f;
  for (int j = threadIdx.x; j < NN; j += 256) m = fmaxf(m, s2g[b * NN + j]);
  red[threadIdx.x] = m;
  __syncthreads();
  for (int off = 128; off; off >>= 1) {
    if ((int)threadIdx.x < off) red[threadIdx.x] = fmaxf(red[threadIdx.x], red[threadIdx.x + off]);
    __syncthreads();
  }
  if (threadIdx.x == 0) maxs2[b] = red[0];
}

// Per-row: A = e^{s1-m}, A' = e^{0.2 s1 - m}, T = e^{-s1}
// Per-col: B = e^{s2}, B' = e^{0.2 s2}
// w_ij = (B_j >= T_i) ? A_i*B_j : A'_i*B'_j   (no exp, no add in hot loop)
__global__ void k_prep(const float* __restrict__ s1g, const float* __restrict__ s2g,
                       const float* __restrict__ maxs2,
                       float* __restrict__ Ag, float* __restrict__ Apg,
                       float* __restrict__ Tg,
                       float* __restrict__ Bv, float* __restrict__ Bpv) {
  int row = blockIdx.x * 256 + threadIdx.x;
  int b = row >> 12;
  float s1 = s1g[row], s2 = s2g[row];
  float t = s1 + maxs2[b];
  float m = t >= 0.f ? t : LRALPHA * t;
  Ag[row]  = expf(s1 - m);
  Apg[row] = expf(LRALPHA * s1 - m);
  Tg[row]  = expf(-s1);
  Bv[row]  = expf(s2);
  Bpv[row] = expf(LRALPHA * s2);
}

// ---------- fused attention kernel (split-precision MFMA) ----------
// Block: 32 rows x 64 ch. 4 waves split j into quarters; each wave runs two
// 16x16x32 subtiles sharing h-fragments. w and h are hi+lo bf16 pairs;
// acc += w_hi*h_hi + w_hi*h_lo + w_lo*h_hi  (fp32-grade numerator).
// LDS combine + normalize -> out written once by this kernel.
__global__ __launch_bounds__(256) void k_attn(
    const unsigned short* __restrict__ hTh, const unsigned short* __restrict__ hTl,
    const float* __restrict__ Ag, const float* __restrict__ Apg,
    const float* __restrict__ Tg,
    const float* __restrict__ Bv, const float* __restrict__ Bpv,
    float* __restrict__ out) {
  __shared__ float slab[4][32][65];
  __shared__ float l_lds[4][32];

  const int wave = threadIdx.x >> 6;
  const int lane = threadIdx.x & 63;
  const int m = lane & 15;          // A row within subtile / D col (channel)
  const int quad = lane >> 4;
  const int row0 = blockIdx.x * 32; // 512 blocks
  const int b = row0 >> 12;
  const int i0 = row0 + m, i1 = row0 + 16 + m;

  const float Ar0 = Ag[i0], Ap0 = Apg[i0], T0 = Tg[i0];
  const float Ar1 = Ag[i1], Ap1 = Apg[i1], T1 = Tg[i1];

  f32x4 acc00 = {0,0,0,0}, acc01 = {0,0,0,0}, acc02 = {0,0,0,0}, acc03 = {0,0,0,0};
  f32x4 acc10 = {0,0,0,0}, acc11 = {0,0,0,0}, acc12 = {0,0,0,0}, acc13 = {0,0,0,0};
  float l0 = 0.f, l1 = 0.f;

  const int j0 = wave * (NN / 4);                 // within batch
  const int jglob0 = (b << 12);
  const size_t hbase = ((size_t)(b * 64 + m) << 12);

  for (int jc = 0; jc < NN / 4; jc += 32) {
    const int nj = j0 + jc + quad * 8;            // this lane's 8 j (within batch)
    const int jf = jglob0 + nj;

    float4 bA = *(const float4*)(Bv + jf);
    float4 bB = *(const float4*)(Bv + jf + 4);
    float4 pA = *(const float4*)(Bpv + jf);
    float4 pB = *(const float4*)(Bpv + jf + 4);
    float bvv[8] = {bA.x, bA.y, bA.z, bA.w, bB.x, bB.y, bB.z, bB.w};
    float pvv[8] = {pA.x, pA.y, pA.z, pA.w, pB.x, pB.y, pB.z, pB.w};

    bf16x8 af0h, af0l, af1h, af1l;
#pragma unroll
    for (int e = 0; e < 8; ++e) {
      float Bj = bvv[e], Bpj = pvv[e];
      float w0 = (Bj >= T0) ? (Ar0 * Bj) : (Ap0 * Bpj);
      float w1 = (Bj >= T1) ? (Ar1 * Bj) : (Ap1 * Bpj);
      l0 += w0; l1 += w1;
      short w0h = f2bf(w0); af0h[e] = w0h; af0l[e] = f2bf(w0 - bf2f(w0h));
      short w1h = f2bf(w1); af1h[e] = w1h; af1l[e] = f2bf(w1 - bf2f(w1h));
    }

    const unsigned short* hp = hTh + hbase + nj;  // c = m, 8 consecutive j
    const unsigned short* lp = hTl + hbase + nj;
    bf16x8 hh0 = *(const bf16x8*)(hp);
    bf16x8 hh1 = *(const bf16x8*)(hp + ((size_t)16 << 12));
    bf16x8 hh2 = *(const bf16x8*)(hp + ((size_t)32 << 12));
    bf16x8 hh3 = *(const bf16x8*)(hp + ((size_t)48 << 12));
    bf16x8 hl0 = *(const bf16x8*)(lp);
    bf16x8 hl1 = *(const bf16x8*)(lp + ((size_t)16 << 12));
    bf16x8 hl2 = *(const bf16x8*)(lp + ((size_t)32 << 12));
    bf16x8 hl3 = *(const bf16x8*)(lp + ((size_t)48 << 12));

    acc00 = __builtin_amdgcn_mfma_f32_16x16x32_bf16(af0h, hh0, acc00, 0, 0, 0);
    acc00 = __builtin_amdgcn_mfma_f32_16x16x32_bf16(af0h, hl0, acc00, 0, 0, 0);
    acc00 = __builtin_amdgcn_mfma_f32_16x16x32_bf16(af0l, hh0, acc00, 0, 0, 0);
    acc01 = __builtin_amdgcn_mfma_f32_16x16x32_bf16(af0h, hh1, acc01, 0, 0, 0);
    acc01 = __builtin_amdgcn_mfma_f32_16x16x32_bf16(af0h, hl1, acc01, 0, 0, 0);
    acc01 = __builtin_amdgcn_mfma_f32_16x16x32_bf16(af0l, hh1, acc01, 0, 0, 0);
    acc02 = __builtin_amdgcn_mfma_f32_16x16x32_bf16(af0h, hh2, acc02, 0, 0, 0);
    acc02 = __builtin_amdgcn_mfma_f32_16x16x32_bf16(af0h, hl2, acc02, 0, 0, 0);
    acc02 = __builtin_amdgcn_mfma_f32_16x16x32_bf16(af0l, hh2, acc02, 0, 0, 0);
    acc03 = __builtin_amdgcn_mfma_f32_16x16x32_bf16(af0h, hh3, acc03, 0, 0, 0);
    acc03 = __builtin_amdgcn_mfma_f32_16x16x32_bf16(af0h, hl3, acc03, 0, 0, 0);
    acc03 = __builtin_amdgcn_mfma_f32_16x16x32_bf16(af0l, hh3, acc03, 0, 0, 0);
    acc10 = __builtin_amdgcn_mfma_f32_16x16x32_bf16(af1h, hh0, acc10, 0, 0, 0);
    acc10 = __builtin_amdgcn_mfma_f32_16x16x32_bf16(af1h, hl0, acc10, 0, 0, 0);
    acc10 = __builtin_amdgcn_mfma_f32_16x16x32_bf16(af1l, hh0, acc10, 0, 0, 0);
    acc11 = __builtin_amdgcn_mfma_f32_16x16x32_bf16(af1h, hh1, acc11, 0, 0, 0);
    acc11 = __builtin_amdgcn_mfma_f32_16x16x32_bf16(af1h, hl1, acc11, 0, 0, 0);
    acc11 = __builtin_amdgcn_mfma_f32_16x16x32_bf16(af1l, hh1, acc11, 0, 0, 0);
    acc12 = __builtin_amdgcn_mfma_f32_16x16x32_bf16(af1h, hh2, acc12, 0, 0, 0);
    acc12 = __builtin_amdgcn_mfma_f32_16x16x32_bf16(af1h, hl2, acc12, 0, 0, 0);
    acc12 = __builtin_amdgcn_mfma_f32_16x16x32_bf16(af1l, hh2, acc12, 0, 0, 0);
    acc13 = __builtin_amdgcn_mfma_f32_16x16x32_bf16(af1h, hh3, acc13, 0, 0, 0);
    acc13 = __builtin_amdgcn_mfma_f32_16x16x32_bf16(af1h, hl3, acc13, 0, 0, 0);
    acc13 = __builtin_amdgcn_mfma_f32_16x16x32_bf16(af1l, hh3, acc13, 0, 0, 0);
  }

  // combine quads for l (each quad summed a disjoint j subset)
  l0 += __shfl_xor(l0, 16, 64); l0 += __shfl_xor(l0, 32, 64);
  l1 += __shfl_xor(l1, 16, 64); l1 += __shfl_xor(l1, 32, 64);
  if (lane < 16) { l_lds[wave][lane] = l0; l_lds[wave][16 + lane] = l1; }

  // D layout: row = quad*4+reg (i offset), col = m (+16*q for channel quarter)
#pragma unroll
  for (int reg = 0; reg < 4; ++reg) {
    int rl = quad * 4 + reg;
    slab[wave][rl][m]      = acc00[reg];
    slab[wave][rl][m + 16] = acc01[reg];
    slab[wave][rl][m + 32] = acc02[reg];
    slab[wave][rl][m + 48] = acc03[reg];
    slab[wave][16 + rl][m]      = acc10[reg];
    slab[wave][16 + rl][m + 16] = acc11[reg];
    slab[wave][16 + rl][m + 32] = acc12[reg];
    slab[wave][16 + rl][m + 48] = acc13[reg];
  }
  __syncthreads();

  // cross-wave combine + normalize + store (each thread: 8 output elements)
#pragma unroll
  for (int k = 0; k < 8; ++k) {
    int f = threadIdx.x + 256 * k;      // 0..2047
    int rl = f >> 6, c = f & 63;
    float s = slab[0][rl][c] + slab[1][rl][c] + slab[2][rl][c] + slab[3][rl][c];
    float L = l_lds[0][rl] + l_lds[1][rl] + l_lds[2][rl] + l_lds[3][rl];
    out[((size_t)(row0 + rl)) * 64 + c] = s / L;
  }
}

// ---------- launcher ----------

extern "C" void kernel_launch(void* const* d_in, const int* in_sizes, int n_in,
                              void* d_out, int out_size, void* d_ws, size_t ws_size,
                              hipStream_t stream) {
  const float* feat = (const float*)d_in[0];
  // d_in[1] = adj : UNUSED by the reference computation
  const float* W = (const float*)d_in[2];
  const float* a = (const float*)d_in[3];
  float* out = (float*)d_out;

  char* ws = (char*)d_ws;
  size_t off = 0;
  auto carve = [&](size_t bytes) -> char* {
    char* p = ws + off;
    off = (off + bytes + 255) & ~(size_t)255;
    return p;
  };
  float*          h   = (float*)carve((size_t)ROWS * 64 * sizeof(float));          // 4 MB
  unsigned short* hTh = (unsigned short*)carve((size_t)ROWS * 64 * sizeof(unsigned short)); // 2 MB
  unsigned short* hTl = (unsigned short*)carve((size_t)ROWS * 64 * sizeof(unsigned short)); // 2 MB
  float* Wt    = (float*)carve(64 * 64 * sizeof(float));
  float* s1g   = (float*)carve(ROWS * sizeof(float));
  float* s2g   = (float*)carve(ROWS * sizeof(float));
  float* Ag    = (float*)carve(ROWS * sizeof(float));
  float* Apg   = (float*)carve(ROWS * sizeof(float));
  float* Tg    = (float*)carve(ROWS * sizeof(float));
  float* Bv    = (float*)carve(ROWS * sizeof(float));
  float* Bpv   = (float*)carve(ROWS * sizeof(float));
  float* maxs2 = (float*)carve(16 * sizeof(float));

  k_transpose_w<<<16, 256, 0, stream>>>(W, Wt);
  k_h<<<ROWS / 4, 256, 0, stream>>>(feat, Wt, a, h, s1g, s2g);
  k_cvt<<<dim3(NN / 64, BB), 256, 0, stream>>>(h, hTh, hTl);
  k_maxs2<<<BB, 256, 0, stream>>>(s2g, maxs2);
  k_prep<<<ROWS / 256, 256, 0, stream>>>(s1g, s2g, maxs2, Ag, Apg, Tg, Bv, Bpv);
  k_attn<<<ROWS / 32, 256, 0, stream>>>(hTh, hTl, Ag, Apg, Tg, Bv, Bpv, out);
}